// Round 1
// baseline (637.329 us; speedup 1.0000x reference)
//
#include <hip/hip_runtime.h>
#include <hip/hip_bf16.h>
#include <stdint.h>
#include <stddef.h>

#define Bn 4
#define Sn 2048
#define En 1024
#define Hn 16
#define Dn 64
#define DIn 64
#define BSn (Bn*Sn)   // 8192

typedef __attribute__((ext_vector_type(8))) short short8;
typedef __attribute__((ext_vector_type(4))) short short4v;
typedef __attribute__((ext_vector_type(4))) float fx4;

__device__ __forceinline__ short f2bf(float f){
  union U { __hip_bfloat16 h; short s; } u; u.h = __float2bfloat16(f); return u.s;
}
__device__ __forceinline__ float bf2f(short x){
  union U { __hip_bfloat16 h; short s; } u; u.s = x; return __bfloat162float(u.h);
}

__device__ __forceinline__ void async16(const void* g, void* l){
  __builtin_amdgcn_global_load_lds((const __attribute__((address_space(1))) unsigned int*)g,
                                   (__attribute__((address_space(3))) unsigned int*)l, 16, 0, 0);
}

#define MFMA16(a,b,c) __builtin_amdgcn_mfma_f32_16x16x32_bf16((a),(b),(c),0,0,0)

// ---------------- cast f32 -> bf16 (vectorized x4) ----------------
__global__ void cast_bf16_k(const float* __restrict__ in, short* __restrict__ out, int n4){
  int i = blockIdx.x*256 + threadIdx.x;
  if (i >= n4) return;
  fx4 v = ((const fx4*)in)[i];
  short4v o = { f2bf(v[0]), f2bf(v[1]), f2bf(v[2]), f2bf(v[3]) };
  ((short4v*)out)[i] = o;
}

// ---------------- per-(b,s) row prep: F/G bias features, invT, key-mask ----------------
// bias(q,k) = 0.5*assign_q.assign_k + mu_q.mu_k/64 - sq_q/128 - sq_k/128 - 0.5*unc_k  = F_q . G_k
__global__ void prep_rows_k(const float* __restrict__ mu, const float* __restrict__ sigma,
                            const float* __restrict__ assign, const float* __restrict__ explore,
                            const float* __restrict__ exploit, const int* __restrict__ mask,
                            short* __restrict__ F, short* __restrict__ G,
                            float* __restrict__ invT, float* __restrict__ kmaskf){
  int r = blockIdx.x;          // 0..BSn-1
  int lane = threadIdx.x;      // 64
  float muv = mu[(size_t)r*DIn + lane];
  float sgv = sigma[(size_t)r*DIn + lane];
  float sq = muv*muv, sg = sgv;
  #pragma unroll
  for (int m=32; m; m>>=1){ sq += __shfl_xor(sq,m,64); sg += __shfl_xor(sg,m,64); }
  float unc = sg*(1.f/64.f);
  #pragma unroll
  for (int cb=0; cb<128; cb+=64){
    int col = cb + lane;
    float fv, gv;
    if (col < 32){ float a = assign[(size_t)r*32 + col]; fv = 0.5f*a; gv = a; }
    else if (col < 96){ float m2 = mu[(size_t)r*DIn + (col-32)]; fv = m2*(1.f/64.f); gv = m2; }
    else if (col == 96){ fv = -sq*(1.f/128.f); gv = 1.f; }
    else if (col == 97){ fv = 1.f; gv = -(sq*(1.f/128.f) + 0.5f*unc); }
    else { fv = 0.f; gv = 0.f; }
    F[(size_t)r*128 + col] = f2bf(fv);
    G[(size_t)r*128 + col] = f2bf(gv);
  }
  if (lane == 0){
    int mk = mask[r];
    float t = 1.f + 0.5f*explore[r] - 0.5f*exploit[r];
    t = fminf(fmaxf(t, 0.5f), 2.f);
    if (mk) t = 1.f;
    invT[r] = 1.f/t;
    kmaskf[r] = mk ? -1e30f : 0.f;
  }
}

// ---------------- NT GEMM: C[m][n] = sum_k A[m][k]*B[n][k] (+biasv[n]) ----------------
// m97 structure: 128x128 tile, BK=32, global_load_lds width 16, 16 MFMA/k-step.
// EPI 0: bf16 output. EPI 1: f32 output with masked-row zeroing.
template<int EPI>
__global__ __launch_bounds__(256) void gemm_nt_k(
    const short* __restrict__ A, const short* __restrict__ Bm, void* __restrict__ C,
    int M, int N, int Kd, int lda, int ldb, int ldc,
    long sA, long sB, long sC,
    const float* __restrict__ biasv, const int* __restrict__ rowmask)
{
  __shared__ short As[128*32];
  __shared__ short Bs[128*32];
  const short* Ab = A + (size_t)blockIdx.z*sA;
  const short* Bb = Bm + (size_t)blockIdx.z*sB;
  const int tid = threadIdx.x;
  const int wv = tid>>6, lane = tid&63, quad = lane>>4, l16 = lane&15;
  const int m0 = blockIdx.y*128, n0 = blockIdx.x*128;
  const int wm = (wv>>1)*64, wn = (wv&1)*64;
  const int rowL = tid>>2, colL = (tid&3)*8;
  fx4 acc[4][4] = {};
  for (int k0=0; k0<Kd; k0+=32){
    __syncthreads();
    async16(Ab + (size_t)(m0+rowL)*lda    + k0 + colL, &As[tid*8]);
    async16(Ab + (size_t)(m0+64+rowL)*lda + k0 + colL, &As[2048 + tid*8]);
    async16(Bb + (size_t)(n0+rowL)*ldb    + k0 + colL, &Bs[tid*8]);
    async16(Bb + (size_t)(n0+64+rowL)*ldb + k0 + colL, &Bs[2048 + tid*8]);
    __syncthreads();
    short8 af[4], bfr[4];
    #pragma unroll
    for (int mi=0; mi<4; mi++) af[mi]  = *(const short8*)&As[(wm+mi*16+l16)*32 + quad*8];
    #pragma unroll
    for (int ni=0; ni<4; ni++) bfr[ni] = *(const short8*)&Bs[(wn+ni*16+l16)*32 + quad*8];
    #pragma unroll
    for (int mi=0; mi<4; mi++)
      #pragma unroll
      for (int ni=0; ni<4; ni++)
        acc[mi][ni] = MFMA16(af[mi], bfr[ni], acc[mi][ni]);
  }
  #pragma unroll
  for (int mi=0; mi<4; mi++){
    #pragma unroll
    for (int ni=0; ni<4; ni++){
      #pragma unroll
      for (int rg=0; rg<4; rg++){
        int row = m0 + wm + mi*16 + quad*4 + rg;     // C/D layout: row = quad*4+reg (m89-verified)
        int col = n0 + wn + ni*16 + l16;             //             col = lane&15
        float v = acc[mi][ni][rg];
        if (biasv) v += biasv[col];
        if (EPI == 0){
          ((short*)C + (size_t)blockIdx.z*sC)[(size_t)row*ldc + col] = f2bf(v);
        } else {
          if (rowmask[row]) v = 0.f;
          ((float*)C)[(size_t)row*ldc + col] = v;
        }
      }
    }
  }
}

// ---------------- flash attention with fused bias / temperature / key-mask ----------------
// grid (S/64, B*H); 4 waves; wave w owns q rows [q0+16w, q0+16w+16); k-tiles of 64.
__global__ __launch_bounds__(256) void flash_attn_k(
    const short* __restrict__ Qg, const short* __restrict__ Kg, const short* __restrict__ Vg,
    const short* __restrict__ biasM, const float* __restrict__ invT,
    const float* __restrict__ kmaskf, short* __restrict__ AO)
{
  const int LQ = 80;   // padded stride (16B-aligned, breaks 128B-stride bank pathology)
  const int LB = 72;
  __shared__ short Qs[64*80];
  __shared__ short Ks[64*80];
  __shared__ short Vt[64*80];      // transposed: Vt[d][k]
  __shared__ short Bsh[64*72];     // bias tile [q][k]
  __shared__ short Ps[4][16*80];   // per-wave P round-trip (C-layout -> A-layout)
  __shared__ float kms[64];
  const int tid = threadIdx.x, wv = tid>>6, lane = tid&63, quad = lane>>4, l16 = lane&15;
  const int q0 = blockIdx.x*64;
  const int b = blockIdx.y / Hn, h = blockIdx.y % Hn;
  const short* Qb = Qg + (size_t)b*Sn*En + h*64;
  const short* Kb = Kg + (size_t)b*Sn*En + h*64;
  const short* Vb = Vg + (size_t)b*Sn*En + h*64;
  const short* Bb = biasM + (size_t)b*Sn*Sn;

  #pragma unroll
  for (int i=0;i<2;i++){
    int idx = i*256 + tid, rr = idx>>3, ch = idx&7;
    *(fx4*)&Qs[rr*LQ + ch*8] = *(const fx4*)(Qb + (size_t)(q0+rr)*En + ch*8);
  }
  __syncthreads();
  short8 qa0 = *(const short8*)&Qs[(wv*16+l16)*LQ + quad*8];
  short8 qa1 = *(const short8*)&Qs[(wv*16+l16)*LQ + 32 + quad*8];
  float invTr[4];
  #pragma unroll
  for (int rg=0; rg<4; rg++) invTr[rg] = invT[b*Sn + q0 + wv*16 + quad*4 + rg];
  fx4 o[4] = {};
  float mrow[4], lrow[4];
  #pragma unroll
  for (int rg=0; rg<4; rg++){ mrow[rg] = -1e30f; lrow[rg] = 0.f; }

  for (int kt=0; kt<Sn; kt+=64){
    __syncthreads();
    #pragma unroll
    for (int i=0;i<2;i++){
      int idx = i*256 + tid, rr = idx>>3, ch = idx&7;
      *(fx4*)&Ks[rr*LQ + ch*8] = *(const fx4*)(Kb + (size_t)(kt+rr)*En + ch*8);
      short8 tv = *(const short8*)(Vb + (size_t)(kt+rr)*En + ch*8);
      #pragma unroll
      for (int j=0;j<8;j++) Vt[(ch*8+j)*LQ + rr] = tv[j];
      *(fx4*)&Bsh[rr*LB + ch*8] = *(const fx4*)(Bb + (size_t)(q0+rr)*Sn + kt + ch*8);
    }
    if (tid < 64) kms[tid] = kmaskf[b*Sn + kt + tid];
    __syncthreads();

    // S = Q.K^T  (per wave: 16q x 64k)
    fx4 sacc[4] = {};
    #pragma unroll
    for (int n=0;n<4;n++){
      short8 kb0 = *(const short8*)&Ks[(n*16+l16)*LQ + quad*8];
      short8 kb1 = *(const short8*)&Ks[(n*16+l16)*LQ + 32 + quad*8];
      sacc[n] = MFMA16(qa0, kb0, sacc[n]);
      sacc[n] = MFMA16(qa1, kb1, sacc[n]);
    }
    // logits = (S/8 + bias) * invT_q  + key-mask(-1e30)
    float ls[4][4];
    float rmax[4] = {-1e30f,-1e30f,-1e30f,-1e30f};
    #pragma unroll
    for (int n=0;n<4;n++){
      float km = kms[n*16 + l16];
      #pragma unroll
      for (int rg=0; rg<4; rg++){
        float bias = bf2f(Bsh[(wv*16 + quad*4 + rg)*LB + n*16 + l16]);
        float v = (sacc[n][rg]*0.125f + bias)*invTr[rg] + km;
        ls[n][rg] = v;
        rmax[rg] = fmaxf(rmax[rg], v);
      }
    }
    #pragma unroll
    for (int rg=0; rg<4; rg++){
      #pragma unroll
      for (int msk=1; msk<16; msk<<=1) rmax[rg] = fmaxf(rmax[rg], __shfl_xor(rmax[rg], msk, 64));
    }
    float alpha[4];
    #pragma unroll
    for (int rg=0; rg<4; rg++){
      float mn = fmaxf(mrow[rg], rmax[rg]);
      alpha[rg] = __expf(mrow[rg] - mn);
      mrow[rg] = mn;
    }
    float rsum[4] = {0.f,0.f,0.f,0.f};
    #pragma unroll
    for (int n=0;n<4;n++)
      #pragma unroll
      for (int rg=0; rg<4; rg++){
        float p = __expf(ls[n][rg] - mrow[rg]);
        ls[n][rg] = p;
        rsum[rg] += p;
      }
    #pragma unroll
    for (int rg=0; rg<4; rg++){
      #pragma unroll
      for (int msk=1; msk<16; msk<<=1) rsum[rg] += __shfl_xor(rsum[rg], msk, 64);
      lrow[rg] = lrow[rg]*alpha[rg] + rsum[rg];
    }
    #pragma unroll
    for (int nd=0; nd<4; nd++)
      #pragma unroll
      for (int rg=0; rg<4; rg++) o[nd][rg] *= alpha[rg];
    // P: C-layout -> LDS -> A-layout (wave-local, no barrier needed)
    #pragma unroll
    for (int n=0;n<4;n++)
      #pragma unroll
      for (int rg=0; rg<4; rg++)
        Ps[wv][(quad*4+rg)*LQ + n*16 + l16] = f2bf(ls[n][rg]);
    short8 pa0 = *(const short8*)&Ps[wv][l16*LQ + quad*8];
    short8 pa1 = *(const short8*)&Ps[wv][l16*LQ + 32 + quad*8];
    #pragma unroll
    for (int nd=0; nd<4; nd++){
      short8 vb0 = *(const short8*)&Vt[(nd*16+l16)*LQ + quad*8];
      short8 vb1 = *(const short8*)&Vt[(nd*16+l16)*LQ + 32 + quad*8];
      o[nd] = MFMA16(pa0, vb0, o[nd]);
      o[nd] = MFMA16(pa1, vb1, o[nd]);
    }
  }
  short* AOb = AO + (size_t)b*Sn*En + h*64;
  float linv[4];
  #pragma unroll
  for (int rg=0; rg<4; rg++) linv[rg] = 1.f/fmaxf(lrow[rg], 1e-8f);
  #pragma unroll
  for (int nd=0; nd<4; nd++)
    #pragma unroll
    for (int rg=0; rg<4; rg++)
      AOb[(size_t)(q0 + wv*16 + quad*4 + rg)*En + nd*16 + l16] = f2bf(o[nd][rg]*linv[rg]);
}

extern "C" void kernel_launch(void* const* d_in, const int* in_sizes, int n_in,
                              void* d_out, int out_size, void* d_ws, size_t ws_size,
                              hipStream_t stream)
{
  const float* his     = (const float*)d_in[0];
  const int*   mask    = (const int*)  d_in[1];
  const float* mu      = (const float*)d_in[2];
  const float* sigma   = (const float*)d_in[3];
  const float* assign  = (const float*)d_in[4];
  const float* explore = (const float*)d_in[5];
  const float* exploit = (const float*)d_in[6];
  const float* Wq = (const float*)d_in[7];  const float* bq = (const float*)d_in[8];
  const float* Wk = (const float*)d_in[9];  const float* bk = (const float*)d_in[10];
  const float* Wv = (const float*)d_in[11]; const float* bv = (const float*)d_in[12];
  const float* Wo = (const float*)d_in[13]; const float* bo = (const float*)d_in[14];

  char* w = (char*)d_ws;
  size_t off = 0;
  auto alloc = [&](size_t bytes){ void* p = w + off; off += (bytes + 255) & ~(size_t)255; return p; };
  short* Xb    = (short*)alloc((size_t)BSn*En*2);
  short* Wqb   = (short*)alloc((size_t)En*En*2);
  short* Wkb   = (short*)alloc((size_t)En*En*2);
  short* Wvb   = (short*)alloc((size_t)En*En*2);
  short* Wob   = (short*)alloc((size_t)En*En*2);
  short* Qb    = (short*)alloc((size_t)BSn*En*2);
  short* Kb    = (short*)alloc((size_t)BSn*En*2);
  short* Vb    = (short*)alloc((size_t)BSn*En*2);
  short* AO    = (short*)alloc((size_t)BSn*En*2);
  short* F     = (short*)alloc((size_t)BSn*128*2);
  short* G     = (short*)alloc((size_t)BSn*128*2);
  short* biasM = (short*)alloc((size_t)Bn*Sn*Sn*2);
  float* invT  = (float*)alloc((size_t)BSn*4);
  float* kmf   = (float*)alloc((size_t)BSn*4);
  (void)ws_size; (void)in_sizes; (void)n_in; (void)out_size;   // ~124 MiB of ws used

  // casts
  cast_bf16_k<<<(BSn*En/4 + 255)/256, 256, 0, stream>>>(his, Xb, BSn*En/4);
  cast_bf16_k<<<(En*En/4 + 255)/256, 256, 0, stream>>>(Wq, Wqb, En*En/4);
  cast_bf16_k<<<(En*En/4 + 255)/256, 256, 0, stream>>>(Wk, Wkb, En*En/4);
  cast_bf16_k<<<(En*En/4 + 255)/256, 256, 0, stream>>>(Wv, Wvb, En*En/4);
  cast_bf16_k<<<(En*En/4 + 255)/256, 256, 0, stream>>>(Wo, Wob, En*En/4);
  // bias features + temperature + key mask
  prep_rows_k<<<BSn, 64, 0, stream>>>(mu, sigma, assign, explore, exploit, mask, F, G, invT, kmf);
  // Q,K,V projections (NT: X @ W^T + b)
  gemm_nt_k<0><<<dim3(En/128, BSn/128, 1), 256, 0, stream>>>(Xb, Wqb, Qb, BSn, En, En, En, En, En, 0,0,0, bq, nullptr);
  gemm_nt_k<0><<<dim3(En/128, BSn/128, 1), 256, 0, stream>>>(Xb, Wkb, Kb, BSn, En, En, En, En, En, 0,0,0, bk, nullptr);
  gemm_nt_k<0><<<dim3(En/128, BSn/128, 1), 256, 0, stream>>>(Xb, Wvb, Vb, BSn, En, En, En, En, En, 0,0,0, bv, nullptr);
  // bias matrix per batch: biasM[b] = F[b] @ G[b]^T  (2048x2048x128)
  gemm_nt_k<0><<<dim3(Sn/128, Sn/128, Bn), 256, 0, stream>>>(F, G, biasM, Sn, Sn, 128, 128, 128, Sn,
                                                             (long)Sn*128, (long)Sn*128, (long)Sn*Sn, nullptr, nullptr);
  // fused attention
  flash_attn_k<<<dim3(Sn/64, Bn*Hn), 256, 0, stream>>>(Qb, Kb, Vb, biasM, invT, kmf, AO);
  // output projection + bo + masked-row zeroing, f32 out
  gemm_nt_k<1><<<dim3(En/128, BSn/128, 1), 256, 0, stream>>>(AO, Wob, d_out, BSn, En, En, En, En, En, 0,0,0, bo, mask);
}

// Round 2
// 465.158 us; speedup vs baseline: 1.3701x; 1.3701x over previous
//
#include <hip/hip_runtime.h>
#include <hip/hip_bf16.h>
#include <stdint.h>
#include <stddef.h>

#define Bn 4
#define Sn 2048
#define En 1024
#define Hn 16
#define DIn 64
#define BSn (Bn*Sn)   // 8192

typedef __attribute__((ext_vector_type(8))) short short8;
typedef __attribute__((ext_vector_type(4))) short short4v;
typedef __attribute__((ext_vector_type(4))) float fx4;
typedef __attribute__((ext_vector_type(8))) _Float16 half8;
typedef __attribute__((ext_vector_type(4))) _Float16 half4;

__device__ __forceinline__ short f2bf(float f){
  union U { __hip_bfloat16 h; short s; } u; u.h = __float2bfloat16(f); return u.s;
}

__device__ __forceinline__ void async16(const void* g, void* l){
  __builtin_amdgcn_global_load_lds((const __attribute__((address_space(1))) unsigned int*)g,
                                   (__attribute__((address_space(3))) unsigned int*)l, 16, 0, 0);
}

__device__ __forceinline__ fx4 mfma_bf(short8 a, short8 b, fx4 c){
  return __builtin_amdgcn_mfma_f32_16x16x32_bf16(a, b, c, 0, 0, 0);
}
__device__ __forceinline__ fx4 mfma_h(short8 a, short8 b, fx4 c){
  return __builtin_amdgcn_mfma_f32_16x16x32_f16(__builtin_bit_cast(half8, a),
                                                __builtin_bit_cast(half8, b), c, 0, 0, 0);
}

// ---------------- cast f32 -> bf16 (vectorized x4) ----------------
__global__ void cast_bf16_k(const float* __restrict__ in, short* __restrict__ out, int n4){
  int i = blockIdx.x*256 + threadIdx.x;
  if (i >= n4) return;
  fx4 v = ((const fx4*)in)[i];
  short4v o = { f2bf(v[0]), f2bf(v[1]), f2bf(v[2]), f2bf(v[3]) };
  ((short4v*)out)[i] = o;
}

// ---------------- per-(b,s) row prep ----------------
// bias(q,k) = F_q . G_k ; a1v = 0.125*invT ; kmf = keymask - M (M=8 static softmax shift)
__global__ void prep_rows_k(const float* __restrict__ mu, const float* __restrict__ sigma,
                            const float* __restrict__ assign, const float* __restrict__ explore,
                            const float* __restrict__ exploit, const int* __restrict__ mask,
                            _Float16* __restrict__ F, _Float16* __restrict__ G,
                            float* __restrict__ a1v, float* __restrict__ kmf){
  int r = blockIdx.x;          // 0..BSn-1
  int lane = threadIdx.x;      // 64
  float muv = mu[(size_t)r*DIn + lane];
  float sgv = sigma[(size_t)r*DIn + lane];
  float sq = muv*muv, sg = sgv;
  #pragma unroll
  for (int m=32; m; m>>=1){ sq += __shfl_xor(sq,m,64); sg += __shfl_xor(sg,m,64); }
  float unc = sg*(1.f/64.f);
  #pragma unroll
  for (int cb=0; cb<128; cb+=64){
    int col = cb + lane;
    float fv, gv;
    if (col < 32){ float a = assign[(size_t)r*32 + col]; fv = 0.5f*a; gv = a; }
    else if (col < 96){ float m2 = mu[(size_t)r*DIn + (col-32)]; fv = m2*(1.f/64.f); gv = m2; }
    else if (col == 96){ fv = -sq*(1.f/128.f); gv = 1.f; }
    else if (col == 97){ fv = 1.f; gv = -(sq*(1.f/128.f) + 0.5f*unc); }
    else { fv = 0.f; gv = 0.f; }
    F[(size_t)r*128 + col] = (_Float16)fv;
    G[(size_t)r*128 + col] = (_Float16)gv;
  }
  if (lane == 0){
    int mk = mask[r];
    float t = 1.f + 0.5f*explore[r] - 0.5f*exploit[r];
    t = fminf(fmaxf(t, 0.5f), 2.f);
    if (mk) t = 1.f;
    a1v[r] = 0.125f/t;
    kmf[r] = (mk ? -1e30f : 0.f) - 8.f;
  }
}

// ---------------- NT GEMM: C[m][n] = sum_k A[m][k]*B[n][k] ----------------
// EPI 0: bf16 out (+biasv). EPI 1: f32 out +biasv +rowmask-zero.
// EPI 2: bf16 out transposed per-head -> Vt[b][h][d][s] (+biasv).
// EPI 3: f16 in/out, value*8 (pre-scaled bias matrix), no biasv.
template<int EPI>
__global__ __launch_bounds__(256) void gemm_nt_k(
    const short* __restrict__ A, const short* __restrict__ Bm, void* __restrict__ C,
    int Kd, int lda, int ldb, int ldc,
    long sA, long sB, long sC,
    const float* __restrict__ biasv, const int* __restrict__ rowmask)
{
  __shared__ short As[128*32];
  __shared__ short Bs[128*32];
  const short* Ab = A + (size_t)blockIdx.z*sA;
  const short* Bb = Bm + (size_t)blockIdx.z*sB;
  const int tid = threadIdx.x;
  const int wv = tid>>6, lane = tid&63, quad = lane>>4, l16 = lane&15;
  const int m0 = blockIdx.y*128, n0 = blockIdx.x*128;
  const int wm = (wv>>1)*64, wn = (wv&1)*64;
  const int rowL = tid>>2, colL = (tid&3)*8;
  fx4 acc[4][4] = {};
  for (int k0=0; k0<Kd; k0+=32){
    __syncthreads();
    async16(Ab + (size_t)(m0+rowL)*lda    + k0 + colL, &As[tid*8]);
    async16(Ab + (size_t)(m0+64+rowL)*lda + k0 + colL, &As[2048 + tid*8]);
    async16(Bb + (size_t)(n0+rowL)*ldb    + k0 + colL, &Bs[tid*8]);
    async16(Bb + (size_t)(n0+64+rowL)*ldb + k0 + colL, &Bs[2048 + tid*8]);
    __syncthreads();
    short8 af[4], bfr[4];
    #pragma unroll
    for (int mi=0; mi<4; mi++) af[mi]  = *(const short8*)&As[(wm+mi*16+l16)*32 + quad*8];
    #pragma unroll
    for (int ni=0; ni<4; ni++) bfr[ni] = *(const short8*)&Bs[(wn+ni*16+l16)*32 + quad*8];
    #pragma unroll
    for (int mi=0; mi<4; mi++)
      #pragma unroll
      for (int ni=0; ni<4; ni++){
        if constexpr (EPI == 3) acc[mi][ni] = mfma_h(af[mi], bfr[ni], acc[mi][ni]);
        else                    acc[mi][ni] = mfma_bf(af[mi], bfr[ni], acc[mi][ni]);
      }
  }
  if constexpr (EPI == 2){
    // stage transposed tile in LDS, then coalesced store to Vt[b][h][d][s]
    __shared__ short Ct[128*136];
    #pragma unroll
    for (int mi=0; mi<4; mi++)
      #pragma unroll
      for (int ni=0; ni<4; ni++){
        int lcol = wn + ni*16 + l16;
        int lrow = wm + mi*16 + quad*4;
        float b0 = biasv[n0 + lcol];
        short4v pk;
        #pragma unroll
        for (int rg=0; rg<4; rg++) pk[rg] = f2bf(acc[mi][ni][rg] + b0);
        *(short4v*)&Ct[lcol*136 + lrow] = pk;
      }
    __syncthreads();
    short* Vt = (short*)C;
    int sl = (tid&15)*8;
    int bb = m0 >> 11, s0 = m0 & 2047;
    #pragma unroll
    for (int e8=0; e8<8; e8++){
      int e_l = e8*16 + (tid>>4);
      fx4 val = *(const fx4*)&Ct[e_l*136 + sl];
      int e_g = n0 + e_l;
      size_t dst = ((size_t)(bb*Hn + (e_g>>6))*64 + (e_g&63))*Sn + s0 + sl;
      *(fx4*)&Vt[dst] = val;
    }
  } else {
    #pragma unroll
    for (int mi=0; mi<4; mi++){
      #pragma unroll
      for (int ni=0; ni<4; ni++){
        #pragma unroll
        for (int rg=0; rg<4; rg++){
          int row = m0 + wm + mi*16 + quad*4 + rg;   // C/D: row=quad*4+reg, col=lane&15 (m89)
          int col = n0 + wn + ni*16 + l16;
          float v = acc[mi][ni][rg];
          if constexpr (EPI == 0){
            v += biasv[col];
            ((short*)C)[(size_t)row*ldc + col] = f2bf(v);
          } else if constexpr (EPI == 1){
            v += biasv[col];
            if (rowmask[row]) v = 0.f;
            ((float*)C)[(size_t)row*ldc + col] = v;
          } else { // EPI == 3: f16 out, x8 pre-scale
            ((_Float16*)C + (size_t)blockIdx.z*sC)[(size_t)row*ldc + col] = (_Float16)(v*8.f);
          }
        }
      }
    }
  }
}

// ---------------- flash attention, 128q block, 32q/wave, static-max softmax ----------------
// Vt pre-transposed [b][h][d][s]; bias f16 transposed [b][k][q] pre-scaled x8.
// ones-row 64 in Vts yields row-sums as acc column 64 (nd=4, l16==0).
__global__ __launch_bounds__(256, 3) void flash2_k(
    const short* __restrict__ Qg, const short* __restrict__ Kg, const short* __restrict__ Vtg,
    const _Float16* __restrict__ biasT, const float* __restrict__ a1v,
    const float* __restrict__ kmf, short* __restrict__ AO)
{
  __shared__ short Qs[128*64];
  __shared__ short Ks[64*64];
  __shared__ short Vts[80*64];        // rows 0..63 = d, row 64 = ones, 65..79 scratch
  __shared__ short Ps[4][32*72];      // per-wave P round-trip, pad 72 (16B-aligned rows)
  const int tid = threadIdx.x, wv = tid>>6, lane = tid&63, quad = lane>>4, l16 = lane&15;
  const int q0 = blockIdx.x*128;
  const int b = blockIdx.y >> 4, h = blockIdx.y & 15;
  const short* Qb = Qg + (size_t)b*Sn*En + h*64;
  const short* Kb = Kg + (size_t)b*Sn*En + h*64;
  const short* Vtb = Vtg + (size_t)(b*Hn + h)*64*Sn;
  const _Float16* Bt = biasT + (size_t)b*Sn*Sn;

  if (tid < 16){
    short one = f2bf(1.f);
    *(short4v*)&Vts[64*64 + tid*4] = (short4v){one, one, one, one};
  }
  // stage Q (128x64) with XOR column-block swizzle applied on the GLOBAL side
  #pragma unroll
  for (int rnd=0; rnd<4; rnd++){
    int idx = rnd*256 + tid;
    int r = idx>>3, c = (idx&7) ^ ((idx>>3)&7);
    async16(Qb + (size_t)(q0 + r)*En + c*8, &Qs[idx*8]);
  }
  __syncthreads();
  short8 qa[2][2];
  #pragma unroll
  for (int mi=0; mi<2; mi++)
    #pragma unroll
    for (int kh=0; kh<2; kh++){
      int row = wv*32 + mi*16 + l16;
      int g = kh*4 + quad;
      qa[mi][kh] = *(const short8*)&Qs[row*64 + ((g ^ (row&7))*8)];
    }
  float a1[2][4];
  #pragma unroll
  for (int mi=0; mi<2; mi++)
    #pragma unroll
    for (int rg=0; rg<4; rg++)
      a1[mi][rg] = a1v[b*Sn + q0 + wv*32 + mi*16 + quad*4 + rg];
  fx4 o[2][5] = {};

  for (int kt=0; kt<Sn; kt+=64){
    __syncthreads();
    #pragma unroll
    for (int rnd=0; rnd<2; rnd++){
      int idx = rnd*256 + tid;
      int r = idx>>3, c = (idx&7) ^ ((idx>>3)&7);
      async16(Kb  + (size_t)(kt + r)*En + c*8, &Ks[idx*8]);
      async16(Vtb + (size_t)r*Sn + kt + c*8,   &Vts[idx*8]);
    }
    // bias (f16, pre-scaled x8, [k][q]) + key-mask, direct from global
    float kmM[4];
    half4 bh[2][4];
    #pragma unroll
    for (int n=0; n<4; n++){
      kmM[n] = kmf[b*Sn + kt + n*16 + l16];
      #pragma unroll
      for (int mi=0; mi<2; mi++)
        bh[mi][n] = *(const half4*)&Bt[(size_t)(kt + n*16 + l16)*Sn + q0 + wv*32 + mi*16 + quad*4];
    }
    __syncthreads();
    // S = Q.K^T : 32q x 64k per wave
    fx4 sacc[2][4] = {};
    #pragma unroll
    for (int n=0; n<4; n++)
      #pragma unroll
      for (int kh=0; kh<2; kh++){
        int row = n*16 + l16, g = kh*4 + quad;
        short8 kb = *(const short8*)&Ks[row*64 + ((g ^ (row&7))*8)];
        sacc[0][n] = mfma_bf(qa[0][kh], kb, sacc[0][n]);
        sacc[1][n] = mfma_bf(qa[1][kh], kb, sacc[1][n]);
      }
    // p = exp((qk + 8*bias)*a1 + km - 8) ; static shift, no reductions
    #pragma unroll
    for (int mi=0; mi<2; mi++)
      #pragma unroll
      for (int n=0; n<4; n++)
        #pragma unroll
        for (int rg=0; rg<4; rg++){
          float t = sacc[mi][n][rg] + (float)bh[mi][n][rg];
          float p = __expf(fmaf(t, a1[mi][rg], kmM[n]));
          Ps[wv][(mi*16 + quad*4 + rg)*72 + n*16 + l16] = f2bf(p);
        }
    short8 pa[2][2];
    #pragma unroll
    for (int mi=0; mi<2; mi++)
      #pragma unroll
      for (int kh=0; kh<2; kh++)
        pa[mi][kh] = *(const short8*)&Ps[wv][(mi*16 + l16)*72 + kh*32 + quad*8];
    // O += P @ [V, 1]
    #pragma unroll
    for (int nd=0; nd<5; nd++)
      #pragma unroll
      for (int kh=0; kh<2; kh++){
        int row = nd*16 + l16, g = kh*4 + quad;
        short8 vb = *(const short8*)&Vts[row*64 + ((g ^ (row&7))*8)];
        o[0][nd] = mfma_bf(pa[0][kh], vb, o[0][nd]);
        o[1][nd] = mfma_bf(pa[1][kh], vb, o[1][nd]);
      }
  }
  short* AOb = AO + (size_t)b*Sn*En + h*64;
  #pragma unroll
  for (int mi=0; mi<2; mi++)
    #pragma unroll
    for (int rg=0; rg<4; rg++){
      float s = __shfl(o[mi][4][rg], lane & 48, 64);   // sum column lives at l16==0
      float linv = 1.f / fmaxf(s, 1e-30f);
      #pragma unroll
      for (int nd=0; nd<4; nd++)
        AOb[(size_t)(q0 + wv*32 + mi*16 + quad*4 + rg)*En + nd*16 + l16] = f2bf(o[mi][nd][rg]*linv);
    }
}

extern "C" void kernel_launch(void* const* d_in, const int* in_sizes, int n_in,
                              void* d_out, int out_size, void* d_ws, size_t ws_size,
                              hipStream_t stream)
{
  const float* his     = (const float*)d_in[0];
  const int*   mask    = (const int*)  d_in[1];
  const float* mu      = (const float*)d_in[2];
  const float* sigma   = (const float*)d_in[3];
  const float* assign  = (const float*)d_in[4];
  const float* explore = (const float*)d_in[5];
  const float* exploit = (const float*)d_in[6];
  const float* Wq = (const float*)d_in[7];  const float* bq = (const float*)d_in[8];
  const float* Wk = (const float*)d_in[9];  const float* bk = (const float*)d_in[10];
  const float* Wv = (const float*)d_in[11]; const float* bv = (const float*)d_in[12];
  const float* Wo = (const float*)d_in[13]; const float* bo = (const float*)d_in[14];

  char* w = (char*)d_ws;
  size_t off = 0;
  auto alloc = [&](size_t bytes){ void* p = w + off; off += (bytes + 255) & ~(size_t)255; return p; };
  short*     Xb    = (short*)alloc((size_t)BSn*En*2);
  short*     Wqb   = (short*)alloc((size_t)En*En*2);
  short*     Wkb   = (short*)alloc((size_t)En*En*2);
  short*     Wvb   = (short*)alloc((size_t)En*En*2);
  short*     Wob   = (short*)alloc((size_t)En*En*2);
  short*     Qb    = (short*)alloc((size_t)BSn*En*2);
  short*     Kb    = (short*)alloc((size_t)BSn*En*2);
  short*     Vtg   = (short*)alloc((size_t)BSn*En*2);
  short*     AO    = (short*)alloc((size_t)BSn*En*2);
  _Float16*  F     = (_Float16*)alloc((size_t)BSn*128*2);
  _Float16*  G     = (_Float16*)alloc((size_t)BSn*128*2);
  _Float16*  biasT = (_Float16*)alloc((size_t)Bn*Sn*Sn*2);
  float*     a1vp  = (float*)alloc((size_t)BSn*4);
  float*     kmf   = (float*)alloc((size_t)BSn*4);
  (void)ws_size; (void)in_sizes; (void)n_in; (void)out_size;

  cast_bf16_k<<<(BSn*En/4 + 255)/256, 256, 0, stream>>>(his, Xb, BSn*En/4);
  cast_bf16_k<<<(En*En/4 + 255)/256, 256, 0, stream>>>(Wq, Wqb, En*En/4);
  cast_bf16_k<<<(En*En/4 + 255)/256, 256, 0, stream>>>(Wk, Wkb, En*En/4);
  cast_bf16_k<<<(En*En/4 + 255)/256, 256, 0, stream>>>(Wv, Wvb, En*En/4);
  cast_bf16_k<<<(En*En/4 + 255)/256, 256, 0, stream>>>(Wo, Wob, En*En/4);
  prep_rows_k<<<BSn, 64, 0, stream>>>(mu, sigma, assign, explore, exploit, mask, F, G, a1vp, kmf);
  // Q,K projections (normal layout), V projection (transposed per-head layout)
  gemm_nt_k<0><<<dim3(En/128, BSn/128, 1), 256, 0, stream>>>(Xb, Wqb, Qb, En, En, En, En, 0,0,0, bq, nullptr);
  gemm_nt_k<0><<<dim3(En/128, BSn/128, 1), 256, 0, stream>>>(Xb, Wkb, Kb, En, En, En, En, 0,0,0, bk, nullptr);
  gemm_nt_k<2><<<dim3(En/128, BSn/128, 1), 256, 0, stream>>>(Xb, Wvb, Vtg, En, En, En, En, 0,0,0, bv, nullptr);
  // bias matrix transposed: biasT[b][k][q] = 8 * (G[b] @ F[b]^T), f16
  gemm_nt_k<3><<<dim3(Sn/128, Sn/128, Bn), 256, 0, stream>>>(
      (const short*)G, (const short*)F, biasT, 128, 128, 128, Sn,
      (long)Sn*128, (long)Sn*128, (long)Sn*Sn, nullptr, nullptr);
  flash2_k<<<dim3(Sn/128, Bn*Hn), 256, 0, stream>>>(Qb, Kb, Vtg, biasT, a1vp, kmf, AO);
  gemm_nt_k<1><<<dim3(En/128, BSn/128, 1), 256, 0, stream>>>(AO, Wob, d_out, En, En, En, En, 0,0,0, bo, mask);
}